// Round 4
// baseline (2571.279 us; speedup 1.0000x reference)
//
#include <hip/hip_runtime.h>
#include <cstdint>
#include <cstddef>

#define TOPK 64
#define CAND_CAP 256

typedef unsigned short u16;
typedef __attribute__((ext_vector_type(8))) short bf16x8;   // 8 bf16 = 4 VGPR
typedef __attribute__((ext_vector_type(4))) float f32x4;    // MFMA 16x16 acc

// Monotone map: descending float order == descending unsigned key order.
__device__ __forceinline__ unsigned fkey(float f) {
    unsigned u = __float_as_uint(f);
    return (u & 0x80000000u) ? ~u : (u | 0x80000000u);
}

// bf16 round-to-nearest-even split helpers.
__device__ __forceinline__ u16 f2bf(float f) {
    unsigned u = __float_as_uint(f);
    return (u16)((u + 0x7FFFu + ((u >> 16) & 1u)) >> 16);
}
__device__ __forceinline__ float bf2f(u16 h) {
    return __uint_as_float(((unsigned)h) << 16);
}

// ---------------------------------------------------------------------------
// Kernel A: split x into bf16 hi/lo.
// ---------------------------------------------------------------------------
__global__ __launch_bounds__(256)
void split_x_kernel(const float* __restrict__ x, u16* __restrict__ xh,
                    u16* __restrict__ xl, int n4) {
    int i = blockIdx.x * 256 + threadIdx.x;
    if (i >= n4) return;
    float4 v = ((const float4*)x)[i];
    ushort4 h, l;
    h.x = f2bf(v.x); l.x = f2bf(v.x - bf2f(h.x));
    h.y = f2bf(v.y); l.y = f2bf(v.y - bf2f(h.y));
    h.z = f2bf(v.z); l.z = f2bf(v.z - bf2f(h.z));
    h.w = f2bf(v.w); l.w = f2bf(v.w - bf2f(h.w));
    ((ushort4*)xh)[i] = h;
    ((ushort4*)xl)[i] = l;
}

// ---------------------------------------------------------------------------
// Kernel B: fused per-row norm + bf16 hi/lo split of v_enc (pad rows zeroed).
// ---------------------------------------------------------------------------
__global__ __launch_bounds__(256)
void vnorm_split_kernel(const float* __restrict__ v_enc,
                        const float* __restrict__ g_enc,
                        float* __restrict__ inv_norm,
                        u16* __restrict__ vh, u16* __restrict__ vl,
                        int H, int D) {
    int h = blockIdx.x;
    int t = threadIdx.x;
    int D4 = D >> 2;
    u16* oh = vh + (size_t)h * D;
    u16* ol = vl + (size_t)h * D;
    if (h >= H) {
        ushort4 zz = make_ushort4(0, 0, 0, 0);
        for (int i = t; i < D4; i += 256) {
            ((ushort4*)oh)[i] = zz;
            ((ushort4*)ol)[i] = zz;
        }
        return;
    }
    const float4* row4 = (const float4*)(v_enc + (size_t)h * D);
    float ss = 0.f;
    for (int i = t; i < D4; i += 256) {
        float4 v = row4[i];
        ss += v.x * v.x + v.y * v.y + v.z * v.z + v.w * v.w;
    }
    for (int off = 32; off > 0; off >>= 1) ss += __shfl_down(ss, off, 64);
    __shared__ float s_part[4];
    int lane = t & 63, wv = t >> 6;
    if (lane == 0) s_part[wv] = ss;
    __syncthreads();
    if (t == 0) {
        float tot = s_part[0] + s_part[1] + s_part[2] + s_part[3];
        inv_norm[h] = g_enc[h] / sqrtf(tot);
    }
    for (int i = t; i < D4; i += 256) {
        float4 v = row4[i];
        ushort4 hh, ll;
        hh.x = f2bf(v.x); ll.x = f2bf(v.x - bf2f(hh.x));
        hh.y = f2bf(v.y); ll.y = f2bf(v.y - bf2f(hh.y));
        hh.z = f2bf(v.z); ll.z = f2bf(v.z - bf2f(hh.z));
        hh.w = f2bf(v.w); ll.w = f2bf(v.w - bf2f(hh.w));
        ((ushort4*)oh)[i] = hh;
        ((ushort4*)ol)[i] = ll;
    }
}

// ---------------------------------------------------------------------------
// Kernel C: split-bf16 MFMA GEMM (verified round-1: z passes).
// 128x128 tile, BK=32, 4 waves (2x2), mfma_f32_16x16x32_bf16, 4 cross terms.
// global_load_lds 16B staging; 16B-slot XOR swizzle on BOTH source and read.
// ---------------------------------------------------------------------------
__device__ __forceinline__ void stage_tile_swz(const u16* __restrict__ g, int ldg,
                                               u16* lds, int tid) {
#pragma unroll
    for (int s = 0; s < 2; ++s) {
        int q = tid + (s << 8);
        int row = q >> 2, slot = q & 3;
        int srcslot = slot ^ ((row >> 1) & 3);
        __builtin_amdgcn_global_load_lds(
            (const __attribute__((address_space(1))) unsigned int*)
                (g + (size_t)row * ldg + srcslot * 8),
            (__attribute__((address_space(3))) unsigned int*)(lds + q * 8),
            16, 0, 0);
    }
}

__global__ __launch_bounds__(256)
void enc_gemm_bf16x4(const u16* __restrict__ xh, const u16* __restrict__ xl,
                     const u16* __restrict__ vh, const u16* __restrict__ vl,
                     const float* __restrict__ inv_norm,
                     const float* __restrict__ b_enc,
                     float* __restrict__ z, int N, int D, int H) {
    __shared__ u16 sAh[128 * 32];
    __shared__ u16 sAl[128 * 32];
    __shared__ u16 sBh[128 * 32];
    __shared__ u16 sBl[128 * 32];

    const int tid  = threadIdx.x;
    const int lane = tid & 63;
    const int wid  = tid >> 6;
    const int wr   = wid >> 1, wc = wid & 1;
    const int fr   = lane & 15;
    const int fg   = lane >> 4;
    const int sp   = fg ^ ((fr >> 1) & 3);
    const int m0   = blockIdx.y * 128;
    const int h0   = blockIdx.x * 128;

    const int aoff = (wr * 64 + fr) * 32 + sp * 8;
    const int boff = (wc * 64 + fr) * 32 + sp * 8;

    const u16* pAh = xh + (size_t)m0 * D;
    const u16* pAl = xl + (size_t)m0 * D;
    const u16* pBh = vh + (size_t)h0 * D;
    const u16* pBl = vl + (size_t)h0 * D;

    f32x4 acc[4][4];
#pragma unroll
    for (int i = 0; i < 4; ++i)
#pragma unroll
        for (int j = 0; j < 4; ++j) acc[i][j] = (f32x4)0.f;

    for (int k0 = 0; k0 < D; k0 += 32) {
        stage_tile_swz(pAh + k0, D, sAh, tid);
        stage_tile_swz(pAl + k0, D, sAl, tid);
        stage_tile_swz(pBh + k0, D, sBh, tid);
        stage_tile_swz(pBl + k0, D, sBl, tid);
        __syncthreads();

        bf16x8 ah[4], al[4], bh[4], bl[4];
#pragma unroll
        for (int i = 0; i < 4; ++i) {
            ah[i] = *(const bf16x8*)&sAh[aoff + i * 512];
            al[i] = *(const bf16x8*)&sAl[aoff + i * 512];
            bh[i] = *(const bf16x8*)&sBh[boff + i * 512];
            bl[i] = *(const bf16x8*)&sBl[boff + i * 512];
        }
#pragma unroll
        for (int mi = 0; mi < 4; ++mi)
#pragma unroll
            for (int ni = 0; ni < 4; ++ni) {
                f32x4 c = acc[mi][ni];
                c = __builtin_amdgcn_mfma_f32_16x16x32_bf16(ah[mi], bh[ni], c, 0, 0, 0);
                c = __builtin_amdgcn_mfma_f32_16x16x32_bf16(ah[mi], bl[ni], c, 0, 0, 0);
                c = __builtin_amdgcn_mfma_f32_16x16x32_bf16(al[mi], bh[ni], c, 0, 0, 0);
                c = __builtin_amdgcn_mfma_f32_16x16x32_bf16(al[mi], bl[ni], c, 0, 0, 0);
                acc[mi][ni] = c;
            }
        __syncthreads();
    }

    const int m_base = m0 + wr * 64 + fg * 4;
    const int h_base = h0 + wc * 64 + fr;
#pragma unroll
    for (int ni = 0; ni < 4; ++ni) {
        int h = h_base + ni * 16;
        if (h < H) {
            float sc = inv_norm[h];
            float bb = b_enc[h];
#pragma unroll
            for (int mi = 0; mi < 4; ++mi) {
                size_t base = (size_t)(m_base + mi * 16) * H + h;
#pragma unroll
                for (int r = 0; r < 4; ++r)
                    z[base + (size_t)r * H] = fmaf(acc[mi][ni][r], sc, bb);
            }
        }
    }
}

// ---------------------------------------------------------------------------
// Fallback fp32 path (workspace too small): original kernels.
// ---------------------------------------------------------------------------
__global__ __launch_bounds__(256)
void enc_norm_kernel(const float* __restrict__ v_enc,
                     const float* __restrict__ g_enc,
                     float* __restrict__ inv_norm, int H, int D) {
    int h = blockIdx.x;
    if (h >= H) return;
    const float* row = v_enc + (size_t)h * D;
    float ss = 0.f;
    for (int i = threadIdx.x; i < D; i += blockDim.x) {
        float v = row[i];
        ss += v * v;
    }
    for (int off = 32; off > 0; off >>= 1) ss += __shfl_down(ss, off, 64);
    __shared__ float s_part[4];
    int lane = threadIdx.x & 63, wv = threadIdx.x >> 6;
    if (lane == 0) s_part[wv] = ss;
    __syncthreads();
    if (threadIdx.x == 0) {
        float t = s_part[0] + s_part[1] + s_part[2] + s_part[3];
        inv_norm[h] = g_enc[h] / sqrtf(t);
    }
}

#define BM 128
#define BN 128
#define BK 16

__global__ __launch_bounds__(256)
void enc_gemm_kernel(const float* __restrict__ x,
                     const float* __restrict__ v_enc,
                     const float* __restrict__ inv_norm,
                     const float* __restrict__ b_enc,
                     float* __restrict__ z,
                     int N, int D, int H) {
    __shared__ float As[BK][BM];
    __shared__ float Bs[BK][BN];
    const int tid = threadIdx.x;
    const int m0 = blockIdx.y * BM;
    const int h0 = blockIdx.x * BN;
    const int tx = tid & 15;
    const int ty = tid >> 4;

    float acc[8][8];
#pragma unroll
    for (int i = 0; i < 8; i++)
#pragma unroll
        for (int j = 0; j < 8; j++) acc[i][j] = 0.f;

    for (int k0 = 0; k0 < D; k0 += BK) {
#pragma unroll
        for (int s = 0; s < 2; ++s) {
            int idx = tid + s * 256;
            int row = idx >> 2, kq = (idx & 3) * 4;
            const float4 av = *(const float4*)(x + (size_t)(m0 + row) * D + k0 + kq);
            As[kq + 0][row] = av.x;
            As[kq + 1][row] = av.y;
            As[kq + 2][row] = av.z;
            As[kq + 3][row] = av.w;
        }
#pragma unroll
        for (int s = 0; s < 2; ++s) {
            int idx = tid + s * 256;
            int row = idx >> 2, kq = (idx & 3) * 4;
            int h = h0 + row;
            float4 bv = make_float4(0.f, 0.f, 0.f, 0.f);
            if (h < H) bv = *(const float4*)(v_enc + (size_t)h * D + k0 + kq);
            Bs[kq + 0][row] = bv.x;
            Bs[kq + 1][row] = bv.y;
            Bs[kq + 2][row] = bv.z;
            Bs[kq + 3][row] = bv.w;
        }
        __syncthreads();
#pragma unroll
        for (int k = 0; k < BK; k++) {
            float a[8], b[8];
            *(float4*)&a[0] = *(const float4*)&As[k][ty * 4];
            *(float4*)&a[4] = *(const float4*)&As[k][64 + ty * 4];
            *(float4*)&b[0] = *(const float4*)&Bs[k][tx * 4];
            *(float4*)&b[4] = *(const float4*)&Bs[k][64 + tx * 4];
#pragma unroll
            for (int i = 0; i < 8; i++)
#pragma unroll
                for (int j = 0; j < 8; j++)
                    acc[i][j] = fmaf(a[i], b[j], acc[i][j]);
        }
        __syncthreads();
    }

#pragma unroll
    for (int i = 0; i < 8; i++) {
        int m = m0 + ((i < 4) ? (ty * 4 + i) : (64 + ty * 4 + i - 4));
        size_t base = (size_t)m * H;
        int h_lo = h0 + tx * 4;
        int h_hi = h0 + 64 + tx * 4;
        if (h_lo + 4 <= H) {
            float4 o;
            o.x = fmaf(acc[i][0], inv_norm[h_lo + 0], b_enc[h_lo + 0]);
            o.y = fmaf(acc[i][1], inv_norm[h_lo + 1], b_enc[h_lo + 1]);
            o.z = fmaf(acc[i][2], inv_norm[h_lo + 2], b_enc[h_lo + 2]);
            o.w = fmaf(acc[i][3], inv_norm[h_lo + 3], b_enc[h_lo + 3]);
            *(float4*)(z + base + h_lo) = o;
        } else {
#pragma unroll
            for (int j = 0; j < 4; j++) {
                int h = h_lo + j;
                if (h < H) z[base + h] = fmaf(acc[i][j], inv_norm[h], b_enc[h]);
            }
        }
        if (h_hi + 4 <= H) {
            float4 o;
            o.x = fmaf(acc[i][4], inv_norm[h_hi + 0], b_enc[h_hi + 0]);
            o.y = fmaf(acc[i][5], inv_norm[h_hi + 1], b_enc[h_hi + 1]);
            o.z = fmaf(acc[i][6], inv_norm[h_hi + 2], b_enc[h_hi + 2]);
            o.w = fmaf(acc[i][7], inv_norm[h_hi + 3], b_enc[h_hi + 3]);
            *(float4*)(z + base + h_hi) = o;
        } else {
#pragma unroll
            for (int j = 0; j < 4; j++) {
                int h = h_hi + j;
                if (h < H) z[base + h] = fmaf(acc[i][4 + j], inv_norm[h], b_enc[h]);
            }
        }
    }
}

// ---------------------------------------------------------------------------
// Kernel: out0 = x
// ---------------------------------------------------------------------------
__global__ __launch_bounds__(256)
void copy_kernel(const float4* __restrict__ in, float4* __restrict__ out, int n4) {
    int i = blockIdx.x * blockDim.x + threadIdx.x;
    if (i < n4) out[i] = in[i];
}

// ---------------------------------------------------------------------------
// Kernel: top-K mask with boundary refinement.
// Radix-select kth key on approx z; elements within +/-delta of the boundary
// are re-evaluated with a strict sequential-k fp32 dot (same accumulation
// order as the verified fp32 baseline -> same correlation with the numpy
// reference), then top 'need' picked by (value desc, index asc) — exact
// jax.lax.top_k tie semantics.  delta ~ 150x the split-bf16 approx error.
// ---------------------------------------------------------------------------
__global__ __launch_bounds__(256)
void topk_refine_kernel(const float* __restrict__ z, float* __restrict__ zbar,
                        const float* __restrict__ x,
                        const float* __restrict__ v_enc,
                        const float* __restrict__ inv_norm,
                        const float* __restrict__ b_enc,
                        int H, int D, int k) {
    const int row = blockIdx.x;
    const float* zr = z + (size_t)row * H;
    const int tid = threadIdx.x;
    __shared__ unsigned hist[256];
    __shared__ unsigned sh_pre;
    __shared__ int sh_k;
    __shared__ int sh_nA;
    __shared__ int sh_nC;
    __shared__ int sh_need;
    __shared__ int cand_idx[CAND_CAP];
    __shared__ float cand_val[CAND_CAP];
    __shared__ int sel_idx[TOPK];

    // ---- exact key of k-th largest approx value (MSB-first radix) ----
    unsigned pre = 0;
    int kk = k;
    for (int round = 0; round < 4; ++round) {
        int shift = 24 - 8 * round;
        hist[tid] = 0;
        __syncthreads();
        for (int i = tid; i < H; i += 256) {
            unsigned key = fkey(zr[i]);
            bool match = (round == 0) || ((key >> (shift + 8)) == (pre >> (shift + 8)));
            if (match) atomicAdd(&hist[(key >> shift) & 0xFFu], 1u);
        }
        __syncthreads();
        if (tid == 0) {
            int acc = 0;
            int b = 255;
            for (; b > 0; --b) {
                int c = (int)hist[b];
                if (acc + c >= kk) break;
                acc += c;
            }
            sh_pre = pre | ((unsigned)b << shift);
            sh_k = kk - acc;
        }
        __syncthreads();
        pre = sh_pre;
        kk = sh_k;
        __syncthreads();
    }
    const unsigned ku = pre;
    const float v_kth = __uint_as_float((ku & 0x80000000u) ? (ku & 0x7FFFFFFFu) : ~ku);
    const float delta = 2e-4f * (1.0f + fabsf(v_kth));
    const float hi_thr = v_kth + delta;
    const float lo_thr = v_kth - delta;

    // ---- classify: certain-in (nA) / candidates (nC) ----
    if (tid == 0) { sh_nA = 0; sh_nC = 0; }
    __syncthreads();
    for (int i = tid; i < H; i += 256) {
        float v = zr[i];
        if (v > hi_thr) {
            atomicAdd(&sh_nA, 1);
        } else if (v >= lo_thr) {
            int p = atomicAdd(&sh_nC, 1);
            if (p < CAND_CAP) cand_idx[p] = i;
        }
    }
    __syncthreads();
    const int nA = sh_nA;                        // <= k-1 by construction
    const int nC = min(sh_nC, CAND_CAP);
    int need = k - nA;                           // >= 1
    if (need > nC) need = nC;                    // overflow-graceful (never fires)

    // ---- refine candidates: sequential-k fp32 dot, baseline numerics ----
    const float* xr = x + (size_t)row * D;
    for (int c = tid; c < nC; c += 256) {
        int h = cand_idx[c];
        const float* vr = v_enc + (size_t)h * D;
        float acc = 0.f;
        for (int d = 0; d < D; d += 4) {
            float4 a = *(const float4*)(xr + d);
            float4 b = *(const float4*)(vr + d);
            acc = fmaf(a.x, b.x, acc);
            acc = fmaf(a.y, b.y, acc);
            acc = fmaf(a.z, b.z, acc);
            acc = fmaf(a.w, b.w, acc);
        }
        cand_val[c] = fmaf(acc, inv_norm[h], b_enc[h]);
    }
    __syncthreads();

    // ---- select top-'need' candidates by (val desc, idx asc) ----
    if (tid == 0) {
        for (int t = 0; t < need; ++t) {
            int best = -1;
            float bv = 0.f;
            int bi = 0;
            for (int c = 0; c < nC; ++c) {
                int ci = cand_idx[c];
                if (ci < 0) continue;
                float cv = cand_val[c];
                if (best < 0 || cv > bv || (cv == bv && ci < bi)) {
                    best = c; bv = cv; bi = ci;
                }
            }
            sel_idx[t] = cand_idx[best];
            cand_idx[best] = -1;
        }
        sh_need = need;
    }
    __syncthreads();
    need = sh_need;

    // ---- final mask write ----
    for (int i = tid; i < H; i += 256) {
        float v = zr[i];
        bool keep = (v > hi_thr);
        if (!keep && v >= lo_thr) {
#pragma unroll 1
            for (int t = 0; t < need; ++t)
                if (sel_idx[t] == i) { keep = true; break; }
        }
        zbar[(size_t)row * H + i] = keep ? v : 0.f;
    }
}

// ---------------------------------------------------------------------------
extern "C" void kernel_launch(void* const* d_in, const int* in_sizes, int n_in,
                              void* d_out, int out_size, void* d_ws, size_t ws_size,
                              hipStream_t stream) {
    const float* x     = (const float*)d_in[0];
    const float* v_enc = (const float*)d_in[1];
    const float* g_enc = (const float*)d_in[2];
    const float* b_enc = (const float*)d_in[3];
    // d_in[4] (v_dec) is dead in the forward value: x_recon == x.

    const int H = in_sizes[2];              // 30000
    const int D = in_sizes[1] / H;          // 768
    const int N = in_sizes[0] / D;          // 4096

    float* out0 = (float*)d_out;                    // x_recon == x   [N,D]
    float* z    = out0 + (size_t)N * D;             // z              [N,H]
    float* zbar = z + (size_t)N * H;                // z_bar          [N,H]

    float* inv_norm = (float*)d_ws;                 // [H]

    const int Hpad = ((H + 127) / 128) * 128;
    size_t off0 = ((size_t)H * sizeof(float) + 255) & ~(size_t)255;
    size_t sz_x = (size_t)N * D * sizeof(u16);
    size_t sz_v = (size_t)Hpad * D * sizeof(u16);
    size_t need = off0 + 2 * sz_x + 2 * sz_v;

    bool use_mfma = (ws_size >= need) && (D % 32 == 0) && (N % 128 == 0) && (D % 4 == 0);

    if (use_mfma) {
        u16* xh = (u16*)((char*)d_ws + off0);
        u16* xl = xh + (size_t)N * D;
        u16* vh = xl + (size_t)N * D;
        u16* vl = vh + (size_t)Hpad * D;

        int n4 = (N * D) / 4;
        split_x_kernel<<<(n4 + 255) / 256, 256, 0, stream>>>(x, xh, xl, n4);
        vnorm_split_kernel<<<Hpad, 256, 0, stream>>>(v_enc, g_enc, inv_norm,
                                                     vh, vl, H, D);
        dim3 ggrid(Hpad / 128, N / 128);
        enc_gemm_bf16x4<<<ggrid, 256, 0, stream>>>(xh, xl, vh, vl, inv_norm,
                                                   b_enc, z, N, D, H);
    } else {
        enc_norm_kernel<<<H, 256, 0, stream>>>(v_enc, g_enc, inv_norm, H, D);
        dim3 ggrid((H + BN - 1) / BN, N / BM);
        enc_gemm_kernel<<<ggrid, 256, 0, stream>>>(x, v_enc, inv_norm, b_enc, z, N, D, H);
    }

    int n4o = (N * D) / 4;
    copy_kernel<<<(n4o + 255) / 256, 256, 0, stream>>>((const float4*)x, (float4*)out0, n4o);

    topk_refine_kernel<<<N, 256, 0, stream>>>(z, zbar, x, v_enc, inv_norm,
                                              b_enc, H, D, TOPK);
}

// Round 5
// 1721.859 us; speedup vs baseline: 1.4933x; 1.4933x over previous
//
#include <hip/hip_runtime.h>
#include <cstdint>
#include <cstddef>

#define TOPK 64
#define CAND_CAP 256
#define LIST_CAP 2048
#define PRE_THR 2.0f
#define DELTA 0.025f

typedef unsigned short u16;
typedef __attribute__((ext_vector_type(8))) short bf16x8;   // 8 bf16 = 4 VGPR
typedef __attribute__((ext_vector_type(4))) float f32x4;    // MFMA 16x16 acc

// Monotone map: descending float order == descending unsigned key order.
__device__ __forceinline__ unsigned fkey(float f) {
    unsigned u = __float_as_uint(f);
    return (u & 0x80000000u) ? ~u : (u | 0x80000000u);
}

// bf16 round-to-nearest-even.
__device__ __forceinline__ u16 f2bf(float f) {
    unsigned u = __float_as_uint(f);
    return (u16)((u + 0x7FFFu + ((u >> 16) & 1u)) >> 16);
}

// ---------------------------------------------------------------------------
// Kernel A: xh = bf16(x); out0 = x  (fused copy, single read of x)
// ---------------------------------------------------------------------------
__global__ __launch_bounds__(256)
void split_x_copy_kernel(const float* __restrict__ x, u16* __restrict__ xh,
                         float4* __restrict__ out0, int n4) {
    int i = blockIdx.x * 256 + threadIdx.x;
    if (i >= n4) return;
    float4 v = ((const float4*)x)[i];
    ushort4 h;
    h.x = f2bf(v.x);
    h.y = f2bf(v.y);
    h.z = f2bf(v.z);
    h.w = f2bf(v.w);
    ((ushort4*)xh)[i] = h;
    out0[i] = v;
}

// ---------------------------------------------------------------------------
// Kernel B: fused per-row norm + bf16 quantize of v_enc (pad rows zeroed).
// ---------------------------------------------------------------------------
__global__ __launch_bounds__(256)
void vnorm_q_kernel(const float* __restrict__ v_enc,
                    const float* __restrict__ g_enc,
                    float* __restrict__ inv_norm,
                    u16* __restrict__ vh, int H, int D) {
    int h = blockIdx.x;
    int t = threadIdx.x;
    int D4 = D >> 2;
    u16* oh = vh + (size_t)h * D;
    if (h >= H) {
        ushort4 zz = make_ushort4(0, 0, 0, 0);
        for (int i = t; i < D4; i += 256) ((ushort4*)oh)[i] = zz;
        return;
    }
    const float4* row4 = (const float4*)(v_enc + (size_t)h * D);
    float ss = 0.f;
    for (int i = t; i < D4; i += 256) {
        float4 v = row4[i];
        ss += v.x * v.x + v.y * v.y + v.z * v.z + v.w * v.w;
    }
    for (int off = 32; off > 0; off >>= 1) ss += __shfl_down(ss, off, 64);
    __shared__ float s_part[4];
    int lane = t & 63, wv = t >> 6;
    if (lane == 0) s_part[wv] = ss;
    __syncthreads();
    if (t == 0) {
        float tot = s_part[0] + s_part[1] + s_part[2] + s_part[3];
        inv_norm[h] = g_enc[h] / sqrtf(tot);
    }
    for (int i = t; i < D4; i += 256) {
        float4 v = row4[i];
        ushort4 hh;
        hh.x = f2bf(v.x);
        hh.y = f2bf(v.y);
        hh.z = f2bf(v.z);
        hh.w = f2bf(v.w);
        ((ushort4*)oh)[i] = hh;
    }
}

// ---------------------------------------------------------------------------
// Kernel C: single-bf16 MFMA GEMM (m97 structure: 16 MFMA + 8 ds_read_b128 +
// 4 global_load_lds per K-step).  128x128 tile, BK=32, 4 waves (2x2).
// 16B-slot XOR swizzle applied on BOTH stage source and ds_read address.
// Approx z error (bf16 x and v): std ~1.6e-3 -- handled by topk refine window.
// ---------------------------------------------------------------------------
__device__ __forceinline__ void stage_tile_swz(const u16* __restrict__ g, int ldg,
                                               u16* lds, int tid) {
#pragma unroll
    for (int s = 0; s < 2; ++s) {
        int q = tid + (s << 8);
        int row = q >> 2, slot = q & 3;
        int srcslot = slot ^ ((row >> 1) & 3);
        __builtin_amdgcn_global_load_lds(
            (const __attribute__((address_space(1))) unsigned int*)
                (g + (size_t)row * ldg + srcslot * 8),
            (__attribute__((address_space(3))) unsigned int*)(lds + q * 8),
            16, 0, 0);
    }
}

__global__ __launch_bounds__(256)
void enc_gemm_bf16(const u16* __restrict__ xh, const u16* __restrict__ vh,
                   const float* __restrict__ inv_norm,
                   const float* __restrict__ b_enc,
                   float* __restrict__ z, int N, int D, int H) {
    __shared__ u16 sA[128 * 32];
    __shared__ u16 sB[128 * 32];

    const int tid  = threadIdx.x;
    const int lane = tid & 63;
    const int wid  = tid >> 6;
    const int wr   = wid >> 1, wc = wid & 1;
    const int fr   = lane & 15;
    const int fg   = lane >> 4;
    const int sp   = fg ^ ((fr >> 1) & 3);
    const int m0   = blockIdx.y * 128;
    const int h0   = blockIdx.x * 128;

    const int aoff = (wr * 64 + fr) * 32 + sp * 8;
    const int boff = (wc * 64 + fr) * 32 + sp * 8;

    const u16* pA = xh + (size_t)m0 * D;
    const u16* pB = vh + (size_t)h0 * D;

    f32x4 acc[4][4];
#pragma unroll
    for (int i = 0; i < 4; ++i)
#pragma unroll
        for (int j = 0; j < 4; ++j) acc[i][j] = (f32x4)0.f;

    for (int k0 = 0; k0 < D; k0 += 32) {
        stage_tile_swz(pA + k0, D, sA, tid);
        stage_tile_swz(pB + k0, D, sB, tid);
        __syncthreads();

        bf16x8 a[4], b[4];
#pragma unroll
        for (int i = 0; i < 4; ++i) {
            a[i] = *(const bf16x8*)&sA[aoff + i * 512];
            b[i] = *(const bf16x8*)&sB[boff + i * 512];
        }
#pragma unroll
        for (int mi = 0; mi < 4; ++mi)
#pragma unroll
            for (int ni = 0; ni < 4; ++ni)
                acc[mi][ni] = __builtin_amdgcn_mfma_f32_16x16x32_bf16(
                    a[mi], b[ni], acc[mi][ni], 0, 0, 0);
        __syncthreads();
    }

    // C/D layout: col = lane&15, row = (lane>>4)*4 + reg.
    const int m_base = m0 + wr * 64 + fg * 4;
    const int h_base = h0 + wc * 64 + fr;
#pragma unroll
    for (int ni = 0; ni < 4; ++ni) {
        int h = h_base + ni * 16;
        if (h < H) {
            float sc = inv_norm[h];
            float bb = b_enc[h];
#pragma unroll
            for (int mi = 0; mi < 4; ++mi) {
                size_t base = (size_t)(m_base + mi * 16) * H + h;
#pragma unroll
                for (int r = 0; r < 4; ++r)
                    z[base + (size_t)r * H] = fmaf(acc[mi][ni][r], sc, bb);
            }
        }
    }
}

// ---------------------------------------------------------------------------
// Fallback fp32 path (workspace too small): original kernels.
// ---------------------------------------------------------------------------
__global__ __launch_bounds__(256)
void enc_norm_kernel(const float* __restrict__ v_enc,
                     const float* __restrict__ g_enc,
                     float* __restrict__ inv_norm, int H, int D) {
    int h = blockIdx.x;
    if (h >= H) return;
    const float* row = v_enc + (size_t)h * D;
    float ss = 0.f;
    for (int i = threadIdx.x; i < D; i += blockDim.x) {
        float v = row[i];
        ss += v * v;
    }
    for (int off = 32; off > 0; off >>= 1) ss += __shfl_down(ss, off, 64);
    __shared__ float s_part[4];
    int lane = threadIdx.x & 63, wv = threadIdx.x >> 6;
    if (lane == 0) s_part[wv] = ss;
    __syncthreads();
    if (threadIdx.x == 0) {
        float t = s_part[0] + s_part[1] + s_part[2] + s_part[3];
        inv_norm[h] = g_enc[h] / sqrtf(t);
    }
}

#define BM 128
#define BN 128
#define BK 16

__global__ __launch_bounds__(256)
void enc_gemm_kernel(const float* __restrict__ x,
                     const float* __restrict__ v_enc,
                     const float* __restrict__ inv_norm,
                     const float* __restrict__ b_enc,
                     float* __restrict__ z,
                     int N, int D, int H) {
    __shared__ float As[BK][BM];
    __shared__ float Bs[BK][BN];
    const int tid = threadIdx.x;
    const int m0 = blockIdx.y * BM;
    const int h0 = blockIdx.x * BN;
    const int tx = tid & 15;
    const int ty = tid >> 4;

    float acc[8][8];
#pragma unroll
    for (int i = 0; i < 8; i++)
#pragma unroll
        for (int j = 0; j < 8; j++) acc[i][j] = 0.f;

    for (int k0 = 0; k0 < D; k0 += BK) {
#pragma unroll
        for (int s = 0; s < 2; ++s) {
            int idx = tid + s * 256;
            int row = idx >> 2, kq = (idx & 3) * 4;
            const float4 av = *(const float4*)(x + (size_t)(m0 + row) * D + k0 + kq);
            As[kq + 0][row] = av.x;
            As[kq + 1][row] = av.y;
            As[kq + 2][row] = av.z;
            As[kq + 3][row] = av.w;
        }
#pragma unroll
        for (int s = 0; s < 2; ++s) {
            int idx = tid + s * 256;
            int row = idx >> 2, kq = (idx & 3) * 4;
            int h = h0 + row;
            float4 bv = make_float4(0.f, 0.f, 0.f, 0.f);
            if (h < H) bv = *(const float4*)(v_enc + (size_t)h * D + k0 + kq);
            Bs[kq + 0][row] = bv.x;
            Bs[kq + 1][row] = bv.y;
            Bs[kq + 2][row] = bv.z;
            Bs[kq + 3][row] = bv.w;
        }
        __syncthreads();
#pragma unroll
        for (int k = 0; k < BK; k++) {
            float a[8], b[8];
            *(float4*)&a[0] = *(const float4*)&As[k][ty * 4];
            *(float4*)&a[4] = *(const float4*)&As[k][64 + ty * 4];
            *(float4*)&b[0] = *(const float4*)&Bs[k][tx * 4];
            *(float4*)&b[4] = *(const float4*)&Bs[k][64 + tx * 4];
#pragma unroll
            for (int i = 0; i < 8; i++)
#pragma unroll
                for (int j = 0; j < 8; j++)
                    acc[i][j] = fmaf(a[i], b[j], acc[i][j]);
        }
        __syncthreads();
    }

#pragma unroll
    for (int i = 0; i < 8; i++) {
        int m = m0 + ((i < 4) ? (ty * 4 + i) : (64 + ty * 4 + i - 4));
        size_t base = (size_t)m * H;
        int h_lo = h0 + tx * 4;
        int h_hi = h0 + 64 + tx * 4;
        if (h_lo + 4 <= H) {
            float4 o;
            o.x = fmaf(acc[i][0], inv_norm[h_lo + 0], b_enc[h_lo + 0]);
            o.y = fmaf(acc[i][1], inv_norm[h_lo + 1], b_enc[h_lo + 1]);
            o.z = fmaf(acc[i][2], inv_norm[h_lo + 2], b_enc[h_lo + 2]);
            o.w = fmaf(acc[i][3], inv_norm[h_lo + 3], b_enc[h_lo + 3]);
            *(float4*)(z + base + h_lo) = o;
        } else {
#pragma unroll
            for (int j = 0; j < 4; j++) {
                int h = h_lo + j;
                if (h < H) z[base + h] = fmaf(acc[i][j], inv_norm[h], b_enc[h]);
            }
        }
        if (h_hi + 4 <= H) {
            float4 o;
            o.x = fmaf(acc[i][4], inv_norm[h_hi + 0], b_enc[h_hi + 0]);
            o.y = fmaf(acc[i][5], inv_norm[h_hi + 1], b_enc[h_hi + 1]);
            o.z = fmaf(acc[i][6], inv_norm[h_hi + 2], b_enc[h_hi + 2]);
            o.w = fmaf(acc[i][7], inv_norm[h_hi + 3], b_enc[h_hi + 3]);
            *(float4*)(z + base + h_hi) = o;
        } else {
#pragma unroll
            for (int j = 0; j < 4; j++) {
                int h = h_hi + j;
                if (h < H) z[base + h] = fmaf(acc[i][4 + j], inv_norm[h], b_enc[h]);
            }
        }
    }
}

__global__ __launch_bounds__(256)
void copy_kernel(const float4* __restrict__ in, float4* __restrict__ out, int n4) {
    int i = blockIdx.x * blockDim.x + threadIdx.x;
    if (i < n4) out[i] = in[i];
}

// ---------------------------------------------------------------------------
// Refine helper: sequential-k fp32 dot (baseline numerics).
// ---------------------------------------------------------------------------
__device__ __forceinline__ float refine_dot(const float* __restrict__ xr,
                                            const float* __restrict__ v_enc,
                                            const float* __restrict__ inv_norm,
                                            const float* __restrict__ b_enc,
                                            int h, int D) {
    const float* vr = v_enc + (size_t)h * D;
    float acc = 0.f;
    for (int d = 0; d < D; d += 4) {
        float4 a = *(const float4*)(xr + d);
        float4 b = *(const float4*)(vr + d);
        acc = fmaf(a.x, b.x, acc);
        acc = fmaf(a.y, b.y, acc);
        acc = fmaf(a.z, b.z, acc);
        acc = fmaf(a.w, b.w, acc);
    }
    return fmaf(acc, inv_norm[h], b_enc[h]);
}

// ---------------------------------------------------------------------------
// Kernel: FAST top-K.  2 passes over z:
//   pass 1: collect all z > PRE_THR into an LDS list (expected ~680/row);
//           radix-select kth + classify + refine all on the LDS list.
//   pass 2: read z, write masked zbar (float4 coalesced).
// Any violated invariant (list overflow, cnt<k, window reaches PRE_THR,
// candidate overflow) -> flags[row]=1, fallback kernel redoes the row.
// Window DELTA=0.025 = 2x a 7.8-sigma bound on the bf16 GEMM approx error;
// candidates are re-scored with sequential fp32 dots (exact tie semantics
// (value desc, index asc) == jax.lax.top_k).
// ---------------------------------------------------------------------------
__global__ __launch_bounds__(256)
void topk_fast_kernel(const float* __restrict__ z, float* __restrict__ zbar,
                      const float* __restrict__ x,
                      const float* __restrict__ v_enc,
                      const float* __restrict__ inv_norm,
                      const float* __restrict__ b_enc,
                      int* __restrict__ flags, int H, int D, int k) {
    const int row = blockIdx.x;
    const float* zr = z + (size_t)row * H;
    const int tid = threadIdx.x;

    __shared__ float l_val[LIST_CAP];
    __shared__ int   l_idx[LIST_CAP];
    __shared__ int   sh_cnt;
    __shared__ unsigned hist[256];
    __shared__ unsigned sh_pre;
    __shared__ int sh_k;
    __shared__ int sh_nA, sh_nC, sh_need;
    __shared__ int   cand_idx[CAND_CAP];
    __shared__ float cand_val[CAND_CAP];
    __shared__ int   sel_idx[TOPK];

    if (tid == 0) sh_cnt = 0;
    __syncthreads();

    // ---- pass 1: collect z > PRE_THR ----
    const int H4 = H >> 2;
    for (int i = tid; i < H4; i += 256) {
        float4 v = ((const float4*)zr)[i];
        if (v.x > PRE_THR) { int p = atomicAdd(&sh_cnt, 1); if (p < LIST_CAP) { l_val[p] = v.x; l_idx[p] = i * 4 + 0; } }
        if (v.y > PRE_THR) { int p = atomicAdd(&sh_cnt, 1); if (p < LIST_CAP) { l_val[p] = v.y; l_idx[p] = i * 4 + 1; } }
        if (v.z > PRE_THR) { int p = atomicAdd(&sh_cnt, 1); if (p < LIST_CAP) { l_val[p] = v.z; l_idx[p] = i * 4 + 2; } }
        if (v.w > PRE_THR) { int p = atomicAdd(&sh_cnt, 1); if (p < LIST_CAP) { l_val[p] = v.w; l_idx[p] = i * 4 + 3; } }
    }
    for (int i = H4 * 4 + tid; i < H; i += 256) {
        float v = zr[i];
        if (v > PRE_THR) { int p = atomicAdd(&sh_cnt, 1); if (p < LIST_CAP) { l_val[p] = v; l_idx[p] = i; } }
    }
    __syncthreads();
    const int cnt = sh_cnt;
    if (cnt > LIST_CAP || cnt < k) {       // list incomplete or kth < PRE_THR
        if (tid == 0) flags[row] = 1;
        return;
    }

    // ---- radix-select exact kth key among list (MSB-first, 8-bit) ----
    unsigned pre = 0;
    int kk = k;
    for (int round = 0; round < 4; ++round) {
        int shift = 24 - 8 * round;
        hist[tid] = 0;
        __syncthreads();
        for (int i = tid; i < cnt; i += 256) {
            unsigned key = fkey(l_val[i]);
            bool match = (round == 0) || ((key >> (shift + 8)) == (pre >> (shift + 8)));
            if (match) atomicAdd(&hist[(key >> shift) & 0xFFu], 1u);
        }
        __syncthreads();
        if (tid == 0) {
            int acc = 0;
            int b = 255;
            for (; b > 0; --b) {
                int c = (int)hist[b];
                if (acc + c >= kk) break;
                acc += c;
            }
            sh_pre = pre | ((unsigned)b << shift);
            sh_k = kk - acc;
        }
        __syncthreads();
        pre = sh_pre;
        kk = sh_k;
        __syncthreads();
    }
    const unsigned ku = pre;
    const float v_kth = __uint_as_float((ku & 0x80000000u) ? (ku & 0x7FFFFFFFu) : ~ku);
    const float hi_thr = v_kth + DELTA;
    const float lo_thr = v_kth - DELTA;
    if (lo_thr <= PRE_THR) {               // window may extend below the list
        if (tid == 0) flags[row] = 1;
        return;
    }

    // ---- classify from list ----
    if (tid == 0) { sh_nA = 0; sh_nC = 0; }
    __syncthreads();
    for (int i = tid; i < cnt; i += 256) {
        float v = l_val[i];
        if (v > hi_thr) {
            atomicAdd(&sh_nA, 1);
        } else if (v >= lo_thr) {
            int p = atomicAdd(&sh_nC, 1);
            if (p < CAND_CAP) cand_idx[p] = l_idx[i];
        }
    }
    __syncthreads();
    if (sh_nC > CAND_CAP) {
        if (tid == 0) flags[row] = 1;
        return;
    }
    const int nA = sh_nA;
    const int nC = sh_nC;
    int need = k - nA;                     // >= 1; nC >= need guaranteed
    if (need > nC) need = nC;

    // ---- refine candidates (fp32 sequential dot) ----
    const float* xr = x + (size_t)row * D;
    for (int c = tid; c < nC; c += 256)
        cand_val[c] = refine_dot(xr, v_enc, inv_norm, b_enc, cand_idx[c], D);
    __syncthreads();

    // ---- select top-'need' by (val desc, idx asc); nC ~ 10, serial ok ----
    if (tid == 0) {
        for (int t = 0; t < need; ++t) {
            int best = -1;
            float bv = 0.f;
            int bi = 0;
            for (int c = 0; c < nC; ++c) {
                int ci = cand_idx[c];
                if (ci < 0) continue;
                float cv = cand_val[c];
                if (best < 0 || cv > bv || (cv == bv && ci < bi)) {
                    best = c; bv = cv; bi = ci;
                }
            }
            sel_idx[t] = cand_idx[best];
            cand_idx[best] = -1;
        }
        sh_need = need;
        flags[row] = 0;
    }
    __syncthreads();
    need = sh_need;

    // ---- pass 2: masked write (coalesced float4) ----
    float* zbr = zbar + (size_t)row * H;
    for (int i = tid; i < H4; i += 256) {
        float4 v = ((const float4*)zr)[i];
        float4 o;
#pragma unroll
        for (int c = 0; c < 4; ++c) {
            float vv = (c == 0) ? v.x : (c == 1) ? v.y : (c == 2) ? v.z : v.w;
            bool keep = (vv > hi_thr);
            if (!keep && vv >= lo_thr) {
#pragma unroll 1
                for (int t = 0; t < need; ++t)
                    if (sel_idx[t] == i * 4 + c) { keep = true; break; }
            }
            float ov = keep ? vv : 0.f;
            if (c == 0) o.x = ov; else if (c == 1) o.y = ov;
            else if (c == 2) o.z = ov; else o.w = ov;
        }
        ((float4*)zbr)[i] = o;
    }
    for (int i = H4 * 4 + tid; i < H; i += 256) {
        float v = zr[i];
        bool keep = (v > hi_thr);
        if (!keep && v >= lo_thr) {
            for (int t = 0; t < need; ++t)
                if (sel_idx[t] == i) { keep = true; break; }
        }
        zbr[i] = keep ? v : 0.f;
    }
}

// ---------------------------------------------------------------------------
// Kernel: FALLBACK top-K (flag-gated).  Full-scan 4-round radix + window
// refine -- the round-4-verified algorithm with DELTA window.
// ---------------------------------------------------------------------------
__global__ __launch_bounds__(256)
void topk_fallback_kernel(const float* __restrict__ z, float* __restrict__ zbar,
                          const float* __restrict__ x,
                          const float* __restrict__ v_enc,
                          const float* __restrict__ inv_norm,
                          const float* __restrict__ b_enc,
                          const int* __restrict__ flags, int H, int D, int k) {
    const int row = blockIdx.x;
    if (flags[row] == 0) return;           // fast path handled this row
    const float* zr = z + (size_t)row * H;
    const int tid = threadIdx.x;
    __shared__ unsigned hist[256];
    __shared__ unsigned sh_pre;
    __shared__ int sh_k;
    __shared__ int sh_nA, sh_nC, sh_need;
    __shared__ int   cand_idx[CAND_CAP];
    __shared__ float cand_val[CAND_CAP];
    __shared__ int   sel_idx[TOPK];

    unsigned pre = 0;
    int kk = k;
    for (int round = 0; round < 4; ++round) {
        int shift = 24 - 8 * round;
        hist[tid] = 0;
        __syncthreads();
        for (int i = tid; i < H; i += 256) {
            unsigned key = fkey(zr[i]);
            bool match = (round == 0) || ((key >> (shift + 8)) == (pre >> (shift + 8)));
            if (match) atomicAdd(&hist[(key >> shift) & 0xFFu], 1u);
        }
        __syncthreads();
        if (tid == 0) {
            int acc = 0;
            int b = 255;
            for (; b > 0; --b) {
                int c = (int)hist[b];
                if (acc + c >= kk) break;
                acc += c;
            }
            sh_pre = pre | ((unsigned)b << shift);
            sh_k = kk - acc;
        }
        __syncthreads();
        pre = sh_pre;
        kk = sh_k;
        __syncthreads();
    }
    const unsigned ku = pre;
    const float v_kth = __uint_as_float((ku & 0x80000000u) ? (ku & 0x7FFFFFFFu) : ~ku);
    const float hi_thr = v_kth + DELTA;
    const float lo_thr = v_kth - DELTA;

    if (tid == 0) { sh_nA = 0; sh_nC = 0; }
    __syncthreads();
    for (int i = tid; i < H; i += 256) {
        float v = zr[i];
        if (v > hi_thr) {
            atomicAdd(&sh_nA, 1);
        } else if (v >= lo_thr) {
            int p = atomicAdd(&sh_nC, 1);
            if (p < CAND_CAP) cand_idx[p] = i;
        }
    }
    __syncthreads();
    const int nA = sh_nA;
    const int nC = min(sh_nC, CAND_CAP);
    int need = k - nA;
    if (need > nC) need = nC;

    const float* xr = x + (size_t)row * D;
    for (int c = tid; c < nC; c += 256)
        cand_val[c] = refine_dot(xr, v_enc, inv_norm, b_enc, cand_idx[c], D);
    __syncthreads();

    if (tid == 0) {
        for (int t = 0; t < need; ++t) {
            int best = -1;
            float bv = 0.f;
            int bi = 0;
            for (int c = 0; c < nC; ++c) {
                int ci = cand_idx[c];
                if (ci < 0) continue;
                float cv = cand_val[c];
                if (best < 0 || cv > bv || (cv == bv && ci < bi)) {
                    best = c; bv = cv; bi = ci;
                }
            }
            sel_idx[t] = cand_idx[best];
            cand_idx[best] = -1;
        }
        sh_need = need;
    }
    __syncthreads();
    need = sh_need;

    for (int i = tid; i < H; i += 256) {
        float v = zr[i];
        bool keep = (v > hi_thr);
        if (!keep && v >= lo_thr) {
#pragma unroll 1
            for (int t = 0; t < need; ++t)
                if (sel_idx[t] == i) { keep = true; break; }
        }
        zbar[(size_t)row * H + i] = keep ? v : 0.f;
    }
}

// ---------------------------------------------------------------------------
extern "C" void kernel_launch(void* const* d_in, const int* in_sizes, int n_in,
                              void* d_out, int out_size, void* d_ws, size_t ws_size,
                              hipStream_t stream) {
    const float* x     = (const float*)d_in[0];
    const float* v_enc = (const float*)d_in[1];
    const float* g_enc = (const float*)d_in[2];
    const float* b_enc = (const float*)d_in[3];
    // d_in[4] (v_dec) is dead in the forward value: x_recon == x.

    const int H = in_sizes[2];              // 30000
    const int D = in_sizes[1] / H;          // 768
    const int N = in_sizes[0] / D;          // 4096

    float* out0 = (float*)d_out;                    // x_recon == x   [N,D]
    float* z    = out0 + (size_t)N * D;             // z              [N,H]
    float* zbar = z + (size_t)N * H;                // z_bar          [N,H]

    float* inv_norm = (float*)d_ws;                 // [H]

    const int Hpad = ((H + 127) / 128) * 128;
    size_t off0 = ((size_t)H * sizeof(float) + 255) & ~(size_t)255;  // flags
    size_t off1 = (off0 + (size_t)N * sizeof(int) + 255) & ~(size_t)255;
    size_t sz_x = (size_t)N * D * sizeof(u16);
    size_t sz_v = (size_t)Hpad * D * sizeof(u16);
    size_t need = off1 + sz_x + sz_v;

    int* flags = (int*)((char*)d_ws + off0);

    bool use_mfma = (ws_size >= need) && (D % 32 == 0) && (N % 128 == 0) && (D % 4 == 0);

    int n4 = (N * D) / 4;
    if (use_mfma) {
        u16* xh = (u16*)((char*)d_ws + off1);
        u16* vh = xh + (size_t)N * D;

        split_x_copy_kernel<<<(n4 + 255) / 256, 256, 0, stream>>>(
            x, xh, (float4*)out0, n4);
        vnorm_q_kernel<<<Hpad, 256, 0, stream>>>(v_enc, g_enc, inv_norm, vh, H, D);
        dim3 ggrid(Hpad / 128, N / 128);
        enc_gemm_bf16<<<ggrid, 256, 0, stream>>>(xh, vh, inv_norm, b_enc, z, N, D, H);
    } else {
        enc_norm_kernel<<<H, 256, 0, stream>>>(v_enc, g_enc, inv_norm, H, D);
        dim3 ggrid((H + BN - 1) / BN, N / BM);
        enc_gemm_kernel<<<ggrid, 256, 0, stream>>>(x, v_enc, inv_norm, b_enc, z, N, D, H);
        copy_kernel<<<(n4 + 255) / 256, 256, 0, stream>>>((const float4*)x, (float4*)out0, n4);
    }

    topk_fast_kernel<<<N, 256, 0, stream>>>(z, zbar, x, v_enc, inv_norm,
                                            b_enc, flags, H, D, TOPK);
    topk_fallback_kernel<<<N, 256, 0, stream>>>(z, zbar, x, v_enc, inv_norm,
                                                b_enc, flags, H, D, TOPK);
}